// Round 4
// baseline (415.146 us; speedup 1.0000x reference)
//
#include <hip/hip_runtime.h>
#include <math.h>

#define IMG_W   800
#define IMG_PIX (IMG_W * IMG_W)
#define NEDGE   6000
#define NSRC    4
#define NVIEW   5
// d_out layout (floats):
//   sim loss : [0, NSRC*NEDGE)
//   mask     : [NSRC*NEDGE, 2*NSRC*NEDGE)
//   black    : [2*NSRC*NEDGE, 2*NSRC*NEDGE + NEDGE)
//   p2d1     : [HDR, HDR + 2P)
//   p2d2     : [HDR + 2P, HDR + 10P)
#define HDR (2 * NSRC * NEDGE + NEDGE) // 54000

typedef float vf4 __attribute__((ext_vector_type(4)));

// 8-byte image-row pair, only 4-byte aligned.
struct __attribute__((packed, aligned(4))) f2u { float a, b; };

__device__ __forceinline__ f2u ld2(const float* __restrict__ p) {
    return *(const f2u*)p;
}
// 16B store; nt (wave-uniform) selects non-temporal vs cached.
// Misaligned (32B-offset) streams use cached stores so L2 merges the partial
// 64B lines; NT partial lines go to HBM twice (measured 1.5x WRITE round 1).
__device__ __forceinline__ void st4(float* p, float a, float b, float c, float d,
                                    bool nt) {
    vf4 v; v.x = a; v.y = b; v.z = c; v.w = d;
    if (nt) __builtin_nontemporal_store(v, (vf4*)p);
    else    *(vf4*)p = v;
}

// Single fused kernel: one block per edge.
//  - block computes its own edge params (wave-uniform scalar math)
//  - block computes its own exclusive prefix bg[e] from npe (L2-resident)
//  - 1024-pt chunks, 4 points/thread (pairs at 2t and 512+2t), no scalar tail
//  - per-(edge,view) 64B-alignment selects NT vs cached p2d stores
//  - block-reduce sums/mask, fused finalize
__global__ void __launch_bounds__(256)
points_kernel(const float* __restrict__ sp,
              const float* __restrict__ epnt,
              const float* __restrict__ K,
              const float* __restrict__ T,
              const int* __restrict__ npe,
              const float* __restrict__ imgs,
              float* __restrict__ out,
              int P) {
    const int e = blockIdx.x;
    const int nsamp = npe[e];          // num_h * 20, even, >= 40
    const int nh = nsamp / 20;
    const int t = threadIdx.x;
    const int lane = t & 63, wid = t >> 6;

    __shared__ float DX[1000];         // num_h clipped to [2,1000]
    __shared__ float DY[20];
    __shared__ float rS[4][5];
    __shared__ int   rM[4];
    __shared__ int   redI[4];

    // ---- coord tables (bit-exact vs numpy: f64 divide then f32 cast) ----
    for (int h = t; h < nh; h += 256)
        DX[h] = (float)((double)h / (double)(nh - 1));
    if (t < 20)
        DY[t] = (t < 10) ? -(float)((double)(9 - t) / 9.0)
                         :  (float)((double)(t - 10) / 9.0);

    // ---- exclusive prefix of npe -> this edge's point offset b20 ----
    int partial = 0;
    for (int i = t; i < e; i += 256) partial += npe[i];
#pragma unroll
    for (int off = 32; off > 0; off >>= 1)
        partial += __shfl_down(partial, off);
    if (lane == 0) redI[wid] = partial;
    __syncthreads();                   // covers DX/DY writes too
    const int b20 = redI[0] + redI[1] + redI[2] + redI[3];

    // ---- per-edge projection params (uniform -> scalar regs) ----
    float Ax[NVIEW], Ay[NVIEW], Az[NVIEW], Aw[NVIEW], Bx[NVIEW], By[NVIEW];
    {
        float sx = sp[3 * e], sy = sp[3 * e + 1], sz = sp[3 * e + 2];
        float ex = epnt[3 * e], ey = epnt[3 * e + 1], ez = epnt[3 * e + 2];
#pragma unroll
        for (int v = 0; v < NVIEW; ++v) {
            float as, bs, cs, ae, be, ce;
            if (v == 0) {
                as = K[0] * sx + K[1] * sy + K[2] * sz;
                bs = K[3] * sx + K[4] * sy + K[5] * sz;
                cs = K[6] * sx + K[7] * sy + K[8] * sz;
                ae = K[0] * ex + K[1] * ey + K[2] * ez;
                be = K[3] * ex + K[4] * ey + K[5] * ez;
                ce = K[6] * ex + K[7] * ey + K[8] * ez;
            } else {
                const float* tt = T + (v - 1) * 12;
                as = tt[0] * sx + tt[1] * sy + tt[2] * sz + tt[3];
                bs = tt[4] * sx + tt[5] * sy + tt[6] * sz + tt[7];
                cs = tt[8] * sx + tt[9] * sy + tt[10] * sz + tt[11];
                ae = tt[0] * ex + tt[1] * ey + tt[2] * ez + tt[3];
                be = tt[4] * ex + tt[5] * ey + tt[6] * ez + tt[7];
                ce = tt[8] * ex + tt[9] * ey + tt[10] * ez + tt[11];
            }
            float u0 = as / (cs + 1e-6f);
            float w0 = bs / (cs + 1e-6f);
            float u1 = ae / (ce + 1e-6f);
            float w1 = be / (ce + 1e-6f);
            float dx = u1 - u0, dy = w1 - w0;
            float cxx = dy, cyy = -dx;   // cross([dx,dy,0],[0,0,1])
            float nrm = sqrtf(cxx * cxx + cyy * cyy);
            float inv = 1.f / (nrm + 1e-6f) * (10.0f / (float)IMG_W);
            Ax[v] = u0; Ay[v] = w0; Az[v] = dx; Aw[v] = dy;
            Bx[v] = cxx * inv; By[v] = cyy * inv;
        }
    }

    // ---- per-view store bases + 64B-alignment flags ----
    float* vbase[NVIEW];
    bool   val64[NVIEW];
    {
        size_t gb = (size_t)b20;
        vbase[0] = out + HDR + 2 * gb;
#pragma unroll
        for (int s = 0; s < NSRC; ++s)
            vbase[s + 1] = out + HDR + 2 * (size_t)P + 2 * ((size_t)s * P + gb);
#pragma unroll
        for (int v = 0; v < NVIEW; ++v)
            val64[v] = ((((size_t)vbase[v]) & 63) == 0);
    }

    float accs[NSRC] = {0.f, 0.f, 0.f, 0.f};
    float accB = 0.f;
    unsigned maskAcc = 0x1Fu;

    for (int base = 0; base < nsamp; base += 1024) {
        // pair k=0,1 -> points base+2t,+1 ; pair k=2,3 -> base+512+2t,+1
        int q0 = base + 2 * t;
        int q1 = base + 512 + 2 * t;
        bool v0 = (q0 < nsamp);        // nsamp even => whole pair valid
        bool v1 = (q1 < nsamp);

        float px[4 * NVIEW], py[4 * NVIEW];
#pragma unroll
        for (int k = 0; k < 4; ++k) {
            bool ok = (k < 2) ? v0 : v1;
            if (!ok) continue;
            int p = ((k < 2) ? q0 : q1) + (k & 1);
            int h = p / 20;
            int m = p - h * 20;
            float xk = DX[h];
            float yk = DY[m];
            unsigned mb = 0;
#pragma unroll
            for (int v = 0; v < NVIEW; ++v) {
                float ux = Az[v] * xk + Bx[v] * yk + Ax[v];
                float uy = Aw[v] * xk + By[v] * yk + Ay[v];
                if ((ux > 0.f) && (ux < 1.f) && (uy > 0.f) && (uy < 1.f))
                    mb |= (1u << v);
                px[k * NVIEW + v] = fminf(fmaxf(ux, 0.f), 0.999999f);
                py[k * NVIEW + v] = fminf(fmaxf(uy, 0.f), 0.999999f);
            }
            maskAcc &= mb;
        }

        // p2d stores: lane-contiguous 16B per lane per pair.
#pragma unroll
        for (int v = 0; v < NVIEW; ++v) {
            float* bp = vbase[v] + 2 * base;
            if (v0) st4(bp + 4 * t,
                        px[0 * NVIEW + v], py[0 * NVIEW + v],
                        px[1 * NVIEW + v], py[1 * NVIEW + v], val64[v]);
            if (v1) st4(bp + 1024 + 4 * t,
                        px[2 * NVIEW + v], py[2 * NVIEW + v],
                        px[3 * NVIEW + v], py[3 * NVIEW + v], val64[v]);
        }

        // issue all 40 row-pair gathers; px/py -> wx/wy in place
        f2u r0[4 * NVIEW], r1[4 * NVIEW];
        unsigned hib = 0;
#pragma unroll
        for (int k = 0; k < 4; ++k) {
            bool ok = (k < 2) ? v0 : v1;
            if (!ok) continue;
#pragma unroll
            for (int v = 0; v < NVIEW; ++v) {
                int j = k * NVIEW + v;
                float fx = px[j] * (float)IMG_W - 0.5f;
                float fy = py[j] * (float)IMG_W - 0.5f;
                float xf = floorf(fx), yf = floorf(fy);
                px[j] = fx - xf;
                py[j] = fy - yf;
                int x0 = (int)xf;
                int y0 = (int)yf;
                int xc = min(max(x0, 0), IMG_W - 2);
                int y0i = min(max(y0, 0), IMG_W - 1);
                int y1i = min(y0i + 1, IMG_W - 1);
                if (x0 >= IMG_W - 1) hib |= (1u << j);
                const float* im = imgs + v * IMG_PIX;
                r0[j] = ld2(im + y0i * IMG_W + xc);
                r1[j] = ld2(im + y1i * IMG_W + xc);
            }
        }
        // combine + accumulate
#pragma unroll
        for (int k = 0; k < 4; ++k) {
            bool ok = (k < 2) ? v0 : v1;
            if (!ok) continue;
            float sval[NVIEW];
#pragma unroll
            for (int v = 0; v < NVIEW; ++v) {
                int j = k * NVIEW + v;
                bool hi = (hib >> j) & 1u;
                float v00 = hi ? r0[j].b : r0[j].a;
                float v01 = r0[j].b;
                float v10 = hi ? r1[j].b : r1[j].a;
                float v11 = r1[j].b;
                float wxv = px[j], wyv = py[j];
                sval[v] = (v00 * (1.f - wxv) + v01 * wxv) * (1.f - wyv)
                        + (v10 * (1.f - wxv) + v11 * wxv) * wyv;
            }
            float s1 = sval[0];
            accB += (s1 < 0.01f) ? 1.f : 0.f;
#pragma unroll
            for (int s = 0; s < NSRC; ++s) {
                float d = sval[s + 1] - s1;
                accs[s] += d * d;
            }
        }
    }

    // ---- block reduction: wave shuffles then LDS across 4 waves ----
    int mi = (int)maskAcc;
#pragma unroll
    for (int off = 32; off > 0; off >>= 1) {
        accs[0] += __shfl_down(accs[0], off);
        accs[1] += __shfl_down(accs[1], off);
        accs[2] += __shfl_down(accs[2], off);
        accs[3] += __shfl_down(accs[3], off);
        accB    += __shfl_down(accB, off);
        mi      &= __shfl_down(mi, off);
    }
    if (lane == 0) {
        rS[wid][0] = accs[0]; rS[wid][1] = accs[1];
        rS[wid][2] = accs[2]; rS[wid][3] = accs[3];
        rS[wid][4] = accB;
        rM[wid] = mi;
    }
    __syncthreads();
    if (t == 0) {
        float s0 = 0.f, s1 = 0.f, s2 = 0.f, s3 = 0.f, sB = 0.f;
        int m = 0x1F;
#pragma unroll
        for (int w = 0; w < 4; ++w) {
            s0 += rS[w][0]; s1 += rS[w][1]; s2 += rS[w][2]; s3 += rS[w][3];
            sB += rS[w][4];
            m  &= rM[w];
        }
        float cnt = (float)nsamp;
        out[0 * NEDGE + e] = s0 / cnt;
        out[1 * NEDGE + e] = s1 / cnt;
        out[2 * NEDGE + e] = s2 / cnt;
        out[3 * NEDGE + e] = s3 / cnt;
        bool vm1 = m & 1;
#pragma unroll
        for (int s = 0; s < NSRC; ++s)
            out[NSRC * NEDGE + s * NEDGE + e] =
                (vm1 && ((m >> (s + 1)) & 1)) ? 1.f : 0.f;
        out[2 * NSRC * NEDGE + e] = ((sB / cnt) > 0.5f) ? 1.f : 0.f;
    }
}

extern "C" void kernel_launch(void* const* d_in, const int* in_sizes, int n_in,
                              void* d_out, int out_size, void* d_ws, size_t ws_size,
                              hipStream_t stream) {
    const float* start = (const float*)d_in[0];
    const float* endp  = (const float*)d_in[1];
    const float* imgs  = (const float*)d_in[2];
    const float* trans = (const float*)d_in[3];
    const float* K     = (const float*)d_in[4];
    const int*   npe   = (const int*)d_in[8];
    int P = in_sizes[5];

    float* out = (float*)d_out;
    points_kernel<<<NEDGE, 256, 0, stream>>>(start, endp, K, trans, npe, imgs,
                                             out, P);
}

// Round 5
// 399.754 us; speedup vs baseline: 1.0385x; 1.0385x over previous
//
#include <hip/hip_runtime.h>
#include <math.h>

#define IMG_W   800
#define IMG_PIX (IMG_W * IMG_W)
#define NEDGE   6000
#define NSRC    4
#define NVIEW   5
// d_out layout (floats):
//   sim loss : [0, NSRC*NEDGE)
//   mask     : [NSRC*NEDGE, 2*NSRC*NEDGE)
//   black    : [2*NSRC*NEDGE, 2*NSRC*NEDGE + NEDGE)
//   p2d1     : [HDR, HDR + 2P)
//   p2d2     : [HDR + 2P, HDR + 10P)
#define HDR (2 * NSRC * NEDGE + NEDGE) // 54000

typedef float vf4 __attribute__((ext_vector_type(4)));
typedef float vf2 __attribute__((ext_vector_type(2)));
// <2 x float> load with align(4): backend still selects global_load_dwordx2
// (gfx950 HW supports unaligned global access). One VMEM op per row-pair
// instead of two global_load_dword (round<=4 used a packed struct -> split).
typedef vf2 uvf2 __attribute__((aligned(4)));

__device__ __forceinline__ vf2 ld2(const float* __restrict__ p) {
    return *(const uvf2*)p;
}
// 16B store; nt (wave-uniform) selects non-temporal vs cached.
// Misaligned (32B-offset) streams use cached stores so L2 merges the partial
// 64B lines; NT partial lines go to HBM twice (measured 1.5x WRITE round 1).
__device__ __forceinline__ void st4(float* p, float a, float b, float c, float d,
                                    bool nt) {
    vf4 v; v.x = a; v.y = b; v.z = c; v.w = d;
    if (nt) __builtin_nontemporal_store(v, (vf4*)p);
    else    *(vf4*)p = v;
}

// Kernel A: exclusive prefix sum of num_per_edge -> per-edge point offsets.
// Separate 1-block kernel: fusing this per-block into points_kernel cost
// ~35us aggregate + doubled FETCH (round-4 post-mortem).
__global__ void __launch_bounds__(256)
scan_kernel(const int* __restrict__ npe, int* __restrict__ bg) {
    __shared__ int part[256];
    int t = threadIdx.x;
    int base = t * 24;            // 256*24 = 6144 >= 6000
    int loc[24];
    int s = 0;
#pragma unroll
    for (int i = 0; i < 24; ++i) {
        int idx = base + i;
        int v = (idx < NEDGE) ? npe[idx] : 0;
        loc[i] = s;
        s += v;
    }
    part[t] = s;
    __syncthreads();
    int own = s;
    for (int off = 1; off < 256; off <<= 1) {
        int v = (t >= off) ? part[t - off] : 0;
        __syncthreads();
        part[t] += v;
        __syncthreads();
    }
    int myoff = part[t] - own;    // exclusive prefix of this thread's chunk
#pragma unroll
    for (int i = 0; i < 24; ++i) {
        int idx = base + i;
        if (idx < NEDGE) bg[idx] = myoff + loc[i];
    }
}

// Kernel B: one block per edge.
//  - block computes its own edge params (wave-uniform scalar math)
//  - 1024-pt chunks, 4 points/thread (pairs at 2t and 512+2t), no scalar tail
//  - per-(edge,view) 64B-alignment selects NT vs cached p2d stores
//  - unaligned-dwordx2 row-pair gathers (half the VMEM ops of split dwords)
//  - block-reduce sums/mask, fused finalize
__global__ void __launch_bounds__(256)
points_kernel(const float* __restrict__ sp,
              const float* __restrict__ epnt,
              const float* __restrict__ K,
              const float* __restrict__ T,
              const int* __restrict__ npe,
              const int* __restrict__ bg,
              const float* __restrict__ imgs,
              float* __restrict__ out,
              int P) {
    const int e = blockIdx.x;
    const int nsamp = npe[e];          // num_h * 20, even, >= 40
    const int nh = nsamp / 20;
    const int b20 = bg[e];
    const int t = threadIdx.x;
    const int lane = t & 63, wid = t >> 6;

    __shared__ float DX[1000];         // num_h clipped to [2,1000]
    __shared__ float DY[20];
    __shared__ float rS[4][5];
    __shared__ int   rM[4];

    // ---- coord tables (bit-exact vs numpy: f64 divide then f32 cast) ----
    for (int h = t; h < nh; h += 256)
        DX[h] = (float)((double)h / (double)(nh - 1));
    if (t < 20)
        DY[t] = (t < 10) ? -(float)((double)(9 - t) / 9.0)
                         :  (float)((double)(t - 10) / 9.0);

    // ---- per-edge projection params (uniform -> scalar regs) ----
    float Ax[NVIEW], Ay[NVIEW], Az[NVIEW], Aw[NVIEW], Bx[NVIEW], By[NVIEW];
    {
        float sx = sp[3 * e], sy = sp[3 * e + 1], sz = sp[3 * e + 2];
        float ex = epnt[3 * e], ey = epnt[3 * e + 1], ez = epnt[3 * e + 2];
#pragma unroll
        for (int v = 0; v < NVIEW; ++v) {
            float as, bs, cs, ae, be, ce;
            if (v == 0) {
                as = K[0] * sx + K[1] * sy + K[2] * sz;
                bs = K[3] * sx + K[4] * sy + K[5] * sz;
                cs = K[6] * sx + K[7] * sy + K[8] * sz;
                ae = K[0] * ex + K[1] * ey + K[2] * ez;
                be = K[3] * ex + K[4] * ey + K[5] * ez;
                ce = K[6] * ex + K[7] * ey + K[8] * ez;
            } else {
                const float* tt = T + (v - 1) * 12;
                as = tt[0] * sx + tt[1] * sy + tt[2] * sz + tt[3];
                bs = tt[4] * sx + tt[5] * sy + tt[6] * sz + tt[7];
                cs = tt[8] * sx + tt[9] * sy + tt[10] * sz + tt[11];
                ae = tt[0] * ex + tt[1] * ey + tt[2] * ez + tt[3];
                be = tt[4] * ex + tt[5] * ey + tt[6] * ez + tt[7];
                ce = tt[8] * ex + tt[9] * ey + tt[10] * ez + tt[11];
            }
            float u0 = as / (cs + 1e-6f);
            float w0 = bs / (cs + 1e-6f);
            float u1 = ae / (ce + 1e-6f);
            float w1 = be / (ce + 1e-6f);
            float dx = u1 - u0, dy = w1 - w0;
            float cxx = dy, cyy = -dx;   // cross([dx,dy,0],[0,0,1])
            float nrm = sqrtf(cxx * cxx + cyy * cyy);
            float inv = 1.f / (nrm + 1e-6f) * (10.0f / (float)IMG_W);
            Ax[v] = u0; Ay[v] = w0; Az[v] = dx; Aw[v] = dy;
            Bx[v] = cxx * inv; By[v] = cyy * inv;
        }
    }

    // ---- per-view store bases + 64B-alignment flags ----
    float* vbase[NVIEW];
    bool   val64[NVIEW];
    {
        size_t gb = (size_t)b20;
        vbase[0] = out + HDR + 2 * gb;
#pragma unroll
        for (int s = 0; s < NSRC; ++s)
            vbase[s + 1] = out + HDR + 2 * (size_t)P + 2 * ((size_t)s * P + gb);
#pragma unroll
        for (int v = 0; v < NVIEW; ++v)
            val64[v] = ((((size_t)vbase[v]) & 63) == 0);
    }
    __syncthreads();

    float accs[NSRC] = {0.f, 0.f, 0.f, 0.f};
    float accB = 0.f;
    unsigned maskAcc = 0x1Fu;

    for (int base = 0; base < nsamp; base += 1024) {
        // pair k=0,1 -> points base+2t,+1 ; pair k=2,3 -> base+512+2t,+1
        int q0 = base + 2 * t;
        int q1 = base + 512 + 2 * t;
        bool v0 = (q0 < nsamp);        // nsamp even => whole pair valid
        bool v1 = (q1 < nsamp);

        float px[4 * NVIEW], py[4 * NVIEW];
#pragma unroll
        for (int k = 0; k < 4; ++k) {
            bool ok = (k < 2) ? v0 : v1;
            if (!ok) continue;
            int p = ((k < 2) ? q0 : q1) + (k & 1);
            int h = p / 20;
            int m = p - h * 20;
            float xk = DX[h];
            float yk = DY[m];
            unsigned mb = 0;
#pragma unroll
            for (int v = 0; v < NVIEW; ++v) {
                float ux = Az[v] * xk + Bx[v] * yk + Ax[v];
                float uy = Aw[v] * xk + By[v] * yk + Ay[v];
                if ((ux > 0.f) && (ux < 1.f) && (uy > 0.f) && (uy < 1.f))
                    mb |= (1u << v);
                px[k * NVIEW + v] = fminf(fmaxf(ux, 0.f), 0.999999f);
                py[k * NVIEW + v] = fminf(fmaxf(uy, 0.f), 0.999999f);
            }
            maskAcc &= mb;
        }

        // p2d stores: lane-contiguous 16B per lane per pair.
#pragma unroll
        for (int v = 0; v < NVIEW; ++v) {
            float* bp = vbase[v] + 2 * base;
            if (v0) st4(bp + 4 * t,
                        px[0 * NVIEW + v], py[0 * NVIEW + v],
                        px[1 * NVIEW + v], py[1 * NVIEW + v], val64[v]);
            if (v1) st4(bp + 1024 + 4 * t,
                        px[2 * NVIEW + v], py[2 * NVIEW + v],
                        px[3 * NVIEW + v], py[3 * NVIEW + v], val64[v]);
        }

        // issue all 40 row-pair gathers; px/py -> wx/wy in place
        vf2 r0[4 * NVIEW], r1[4 * NVIEW];
        unsigned hib = 0;
#pragma unroll
        for (int k = 0; k < 4; ++k) {
            bool ok = (k < 2) ? v0 : v1;
            if (!ok) continue;
#pragma unroll
            for (int v = 0; v < NVIEW; ++v) {
                int j = k * NVIEW + v;
                float fx = px[j] * (float)IMG_W - 0.5f;
                float fy = py[j] * (float)IMG_W - 0.5f;
                float xf = floorf(fx), yf = floorf(fy);
                px[j] = fx - xf;
                py[j] = fy - yf;
                int x0 = (int)xf;
                int y0 = (int)yf;
                int xc = min(max(x0, 0), IMG_W - 2);
                int y0i = min(max(y0, 0), IMG_W - 1);
                int y1i = min(y0i + 1, IMG_W - 1);
                if (x0 >= IMG_W - 1) hib |= (1u << j);
                const float* im = imgs + v * IMG_PIX;
                r0[j] = ld2(im + y0i * IMG_W + xc);
                r1[j] = ld2(im + y1i * IMG_W + xc);
            }
        }
        // combine + accumulate
#pragma unroll
        for (int k = 0; k < 4; ++k) {
            bool ok = (k < 2) ? v0 : v1;
            if (!ok) continue;
            float sval[NVIEW];
#pragma unroll
            for (int v = 0; v < NVIEW; ++v) {
                int j = k * NVIEW + v;
                bool hi = (hib >> j) & 1u;
                float v00 = hi ? r0[j].y : r0[j].x;
                float v01 = r0[j].y;
                float v10 = hi ? r1[j].y : r1[j].x;
                float v11 = r1[j].y;
                float wxv = px[j], wyv = py[j];
                sval[v] = (v00 * (1.f - wxv) + v01 * wxv) * (1.f - wyv)
                        + (v10 * (1.f - wxv) + v11 * wxv) * wyv;
            }
            float s1 = sval[0];
            accB += (s1 < 0.01f) ? 1.f : 0.f;
#pragma unroll
            for (int s = 0; s < NSRC; ++s) {
                float d = sval[s + 1] - s1;
                accs[s] += d * d;
            }
        }
    }

    // ---- block reduction: wave shuffles then LDS across 4 waves ----
    int mi = (int)maskAcc;
#pragma unroll
    for (int off = 32; off > 0; off >>= 1) {
        accs[0] += __shfl_down(accs[0], off);
        accs[1] += __shfl_down(accs[1], off);
        accs[2] += __shfl_down(accs[2], off);
        accs[3] += __shfl_down(accs[3], off);
        accB    += __shfl_down(accB, off);
        mi      &= __shfl_down(mi, off);
    }
    if (lane == 0) {
        rS[wid][0] = accs[0]; rS[wid][1] = accs[1];
        rS[wid][2] = accs[2]; rS[wid][3] = accs[3];
        rS[wid][4] = accB;
        rM[wid] = mi;
    }
    __syncthreads();
    if (t == 0) {
        float s0 = 0.f, s1 = 0.f, s2 = 0.f, s3 = 0.f, sB = 0.f;
        int m = 0x1F;
#pragma unroll
        for (int w = 0; w < 4; ++w) {
            s0 += rS[w][0]; s1 += rS[w][1]; s2 += rS[w][2]; s3 += rS[w][3];
            sB += rS[w][4];
            m  &= rM[w];
        }
        float cnt = (float)nsamp;
        out[0 * NEDGE + e] = s0 / cnt;
        out[1 * NEDGE + e] = s1 / cnt;
        out[2 * NEDGE + e] = s2 / cnt;
        out[3 * NEDGE + e] = s3 / cnt;
        bool vm1 = m & 1;
#pragma unroll
        for (int s = 0; s < NSRC; ++s)
            out[NSRC * NEDGE + s * NEDGE + e] =
                (vm1 && ((m >> (s + 1)) & 1)) ? 1.f : 0.f;
        out[2 * NSRC * NEDGE + e] = ((sB / cnt) > 0.5f) ? 1.f : 0.f;
    }
}

extern "C" void kernel_launch(void* const* d_in, const int* in_sizes, int n_in,
                              void* d_out, int out_size, void* d_ws, size_t ws_size,
                              hipStream_t stream) {
    const float* start = (const float*)d_in[0];
    const float* endp  = (const float*)d_in[1];
    const float* imgs  = (const float*)d_in[2];
    const float* trans = (const float*)d_in[3];
    const float* K     = (const float*)d_in[4];
    const int*   npe   = (const int*)d_in[8];
    int P = in_sizes[5];

    int* bg = (int*)d_ws;              // 24000 B

    float* out = (float*)d_out;
    scan_kernel<<<1, 256, 0, stream>>>(npe, bg);
    points_kernel<<<NEDGE, 256, 0, stream>>>(start, endp, K, trans, npe, bg,
                                             imgs, out, P);
}

// Round 6
// 376.095 us; speedup vs baseline: 1.1038x; 1.0629x over previous
//
#include <hip/hip_runtime.h>
#include <math.h>

#define IMG_W   800
#define IMG_PIX (IMG_W * IMG_W)
#define NEDGE   6000
#define NSRC    4
#define NVIEW   5
// d_out layout (floats):
//   sim loss : [0, NSRC*NEDGE)
//   mask     : [NSRC*NEDGE, 2*NSRC*NEDGE)
//   black    : [2*NSRC*NEDGE, 2*NSRC*NEDGE + NEDGE)
//   p2d1     : [HDR, HDR + 2P)
//   p2d2     : [HDR + 2P, HDR + 10P)
#define HDR (2 * NSRC * NEDGE + NEDGE) // 54000

typedef float vf4 __attribute__((ext_vector_type(4)));
typedef float vf2 __attribute__((ext_vector_type(2)));
// <2 x float> load with align(4): backend still selects global_load_dwordx2
// (gfx950 supports unaligned global access). One VMEM op per row-pair
// instead of two global_load_dword. (r5: -24us on the 4pt structure.)
typedef vf2 uvf2 __attribute__((aligned(4)));

__device__ __forceinline__ vf2 ld2(const float* __restrict__ p) {
    return *(const uvf2*)p;
}
// 16B store; nt (wave-uniform) selects non-temporal vs cached.
// Misaligned (32B-offset) streams use cached stores so L2 merges the partial
// 64B lines; NT partial lines go to HBM twice (r1: 367MB vs ideal 244MB;
// align-selected r5: 235MB).
__device__ __forceinline__ void st4(float* p, float a, float b, float c, float d,
                                    bool nt) {
    vf4 v; v.x = a; v.y = b; v.z = c; v.w = d;
    if (nt) __builtin_nontemporal_store(v, (vf4*)p);
    else    *(vf4*)p = v;
}

// Kernel A: exclusive prefix sum of num_per_edge -> per-edge point offsets.
// Kept as a separate 1-block kernel: per-block fused scan cost ~25us
// aggregate VALU (r4 post-mortem, VALUBusy 37->46%).
__global__ void __launch_bounds__(256)
scan_kernel(const int* __restrict__ npe, int* __restrict__ bg) {
    __shared__ int part[256];
    int t = threadIdx.x;
    int base = t * 24;            // 256*24 = 6144 >= 6000
    int loc[24];
    int s = 0;
#pragma unroll
    for (int i = 0; i < 24; ++i) {
        int idx = base + i;
        int v = (idx < NEDGE) ? npe[idx] : 0;
        loc[i] = s;
        s += v;
    }
    part[t] = s;
    __syncthreads();
    int own = s;
    for (int off = 1; off < 256; off <<= 1) {
        int v = (t >= off) ? part[t - off] : 0;
        __syncthreads();
        part[t] += v;
        __syncthreads();
    }
    int myoff = part[t] - own;    // exclusive prefix of this thread's chunk
#pragma unroll
    for (int i = 0; i < 24; ++i) {
        int idx = base + i;
        if (idx < NEDGE) bg[idx] = myoff + loc[i];
    }
}

// Kernel B: one block per edge, 512-pt chunks, 2 points/thread (r3 structure,
// best measured total). Points 2t/2t+1 share h (p even => same DX row):
// one LDS read + shared Az*x+Ax partial per view.
//  - fused edge params (wave-uniform scalar math)
//  - per-(edge,view) 64B-alignment selects NT vs cached p2d stores
//  - unaligned-dwordx2 row-pair gathers
//  - block-reduce sums/mask, fused finalize
__global__ void __launch_bounds__(256)
points_kernel(const float* __restrict__ sp,
              const float* __restrict__ epnt,
              const float* __restrict__ K,
              const float* __restrict__ T,
              const int* __restrict__ npe,
              const int* __restrict__ bg,
              const float* __restrict__ imgs,
              float* __restrict__ out,
              int P) {
    const int e = blockIdx.x;
    const int nsamp = npe[e];          // num_h * 20, even, >= 40
    const int nh = nsamp / 20;
    const int b20 = bg[e];
    const int t = threadIdx.x;
    const int lane = t & 63, wid = t >> 6;

    __shared__ float DX[1000];         // num_h clipped to [2,1000]
    __shared__ float DY[20];
    __shared__ float rS[4][5];
    __shared__ int   rM[4];

    // ---- coord tables (bit-exact vs numpy: f64 divide then f32 cast) ----
    for (int h = t; h < nh; h += 256)
        DX[h] = (float)((double)h / (double)(nh - 1));
    if (t < 20)
        DY[t] = (t < 10) ? -(float)((double)(9 - t) / 9.0)
                         :  (float)((double)(t - 10) / 9.0);

    // ---- per-edge projection params (uniform -> scalar regs) ----
    float Ax[NVIEW], Ay[NVIEW], Az[NVIEW], Aw[NVIEW], Bx[NVIEW], By[NVIEW];
    {
        float sx = sp[3 * e], sy = sp[3 * e + 1], sz = sp[3 * e + 2];
        float ex = epnt[3 * e], ey = epnt[3 * e + 1], ez = epnt[3 * e + 2];
#pragma unroll
        for (int v = 0; v < NVIEW; ++v) {
            float as, bs, cs, ae, be, ce;
            if (v == 0) {
                as = K[0] * sx + K[1] * sy + K[2] * sz;
                bs = K[3] * sx + K[4] * sy + K[5] * sz;
                cs = K[6] * sx + K[7] * sy + K[8] * sz;
                ae = K[0] * ex + K[1] * ey + K[2] * ez;
                be = K[3] * ex + K[4] * ey + K[5] * ez;
                ce = K[6] * ex + K[7] * ey + K[8] * ez;
            } else {
                const float* tt = T + (v - 1) * 12;
                as = tt[0] * sx + tt[1] * sy + tt[2] * sz + tt[3];
                bs = tt[4] * sx + tt[5] * sy + tt[6] * sz + tt[7];
                cs = tt[8] * sx + tt[9] * sy + tt[10] * sz + tt[11];
                ae = tt[0] * ex + tt[1] * ey + tt[2] * ez + tt[3];
                be = tt[4] * ex + tt[5] * ey + tt[6] * ez + tt[7];
                ce = tt[8] * ex + tt[9] * ey + tt[10] * ez + tt[11];
            }
            float u0 = as / (cs + 1e-6f);
            float w0 = bs / (cs + 1e-6f);
            float u1 = ae / (ce + 1e-6f);
            float w1 = be / (ce + 1e-6f);
            float dx = u1 - u0, dy = w1 - w0;
            float cxx = dy, cyy = -dx;   // cross([dx,dy,0],[0,0,1])
            float nrm = sqrtf(cxx * cxx + cyy * cyy);
            float inv = 1.f / (nrm + 1e-6f) * (10.0f / (float)IMG_W);
            Ax[v] = u0; Ay[v] = w0; Az[v] = dx; Aw[v] = dy;
            Bx[v] = cxx * inv; By[v] = cyy * inv;
        }
    }

    // ---- per-view store bases + 64B-alignment flags ----
    float* vbase[NVIEW];
    bool   val64[NVIEW];
    {
        size_t gb = (size_t)b20;
        vbase[0] = out + HDR + 2 * gb;
#pragma unroll
        for (int s = 0; s < NSRC; ++s)
            vbase[s + 1] = out + HDR + 2 * (size_t)P + 2 * ((size_t)s * P + gb);
#pragma unroll
        for (int v = 0; v < NVIEW; ++v)
            val64[v] = ((((size_t)vbase[v]) & 63) == 0);
    }
    __syncthreads();

    float accs[NSRC] = {0.f, 0.f, 0.f, 0.f};
    float accB = 0.f;
    unsigned maskAcc = 0x1Fu;

    for (int base = 0; base < nsamp; base += 512) {
        int p0 = base + 2 * t;
        bool valid = (p0 < nsamp);     // nsamp even => p0+1 also valid

        if (valid) {
            int h = p0 / 20;
            int m0 = p0 - h * 20;      // even => m0+1 < 20, same h
            float xk = DX[h];
            float y0 = DY[m0];
            float y1 = DY[m0 + 1];

            float px[2 * NVIEW], py[2 * NVIEW];
            unsigned mb0 = 0, mb1 = 0;
#pragma unroll
            for (int v = 0; v < NVIEW; ++v) {
                float Sx = fmaf(Az[v], xk, Ax[v]);   // shared across the pair
                float Sy = fmaf(Aw[v], xk, Ay[v]);
                float ux0 = fmaf(Bx[v], y0, Sx);
                float uy0 = fmaf(By[v], y0, Sy);
                float ux1 = fmaf(Bx[v], y1, Sx);
                float uy1 = fmaf(By[v], y1, Sy);
                if ((ux0 > 0.f) && (ux0 < 1.f) && (uy0 > 0.f) && (uy0 < 1.f))
                    mb0 |= (1u << v);
                if ((ux1 > 0.f) && (ux1 < 1.f) && (uy1 > 0.f) && (uy1 < 1.f))
                    mb1 |= (1u << v);
                px[0 * NVIEW + v] = fminf(fmaxf(ux0, 0.f), 0.999999f);
                py[0 * NVIEW + v] = fminf(fmaxf(uy0, 0.f), 0.999999f);
                px[1 * NVIEW + v] = fminf(fmaxf(ux1, 0.f), 0.999999f);
                py[1 * NVIEW + v] = fminf(fmaxf(uy1, 0.f), 0.999999f);
            }
            maskAcc &= mb0 & mb1;

            // p2d stores: lane-contiguous 16B per lane.
#pragma unroll
            for (int v = 0; v < NVIEW; ++v)
                st4(vbase[v] + 2 * base + 4 * t,
                    px[0 * NVIEW + v], py[0 * NVIEW + v],
                    px[1 * NVIEW + v], py[1 * NVIEW + v], val64[v]);

            // issue all 20 row-pair gathers; px/py -> wx/wy in place
            vf2 r0[2 * NVIEW], r1[2 * NVIEW];
            unsigned hib = 0;
#pragma unroll
            for (int k = 0; k < 2; ++k) {
#pragma unroll
                for (int v = 0; v < NVIEW; ++v) {
                    int j = k * NVIEW + v;
                    float fx = px[j] * (float)IMG_W - 0.5f;
                    float fy = py[j] * (float)IMG_W - 0.5f;
                    float xf = floorf(fx), yf = floorf(fy);
                    px[j] = fx - xf;
                    py[j] = fy - yf;
                    int x0 = (int)xf;
                    int y0i = (int)yf;
                    int xc = min(max(x0, 0), IMG_W - 2);
                    int yc0 = min(max(y0i, 0), IMG_W - 1);
                    int yc1 = min(yc0 + 1, IMG_W - 1);
                    if (x0 >= IMG_W - 1) hib |= (1u << j);
                    const float* im = imgs + v * IMG_PIX;
                    r0[j] = ld2(im + yc0 * IMG_W + xc);
                    r1[j] = ld2(im + yc1 * IMG_W + xc);
                }
            }
            // combine + accumulate
#pragma unroll
            for (int k = 0; k < 2; ++k) {
                float sval[NVIEW];
#pragma unroll
                for (int v = 0; v < NVIEW; ++v) {
                    int j = k * NVIEW + v;
                    bool hi = (hib >> j) & 1u;
                    float v00 = hi ? r0[j].y : r0[j].x;
                    float v01 = r0[j].y;
                    float v10 = hi ? r1[j].y : r1[j].x;
                    float v11 = r1[j].y;
                    float wxv = px[j], wyv = py[j];
                    sval[v] = (v00 * (1.f - wxv) + v01 * wxv) * (1.f - wyv)
                            + (v10 * (1.f - wxv) + v11 * wxv) * wyv;
                }
                float s1 = sval[0];
                accB += (s1 < 0.01f) ? 1.f : 0.f;
#pragma unroll
                for (int s = 0; s < NSRC; ++s) {
                    float d = sval[s + 1] - s1;
                    accs[s] += d * d;
                }
            }
        }
    }

    // ---- block reduction: wave shuffles then LDS across 4 waves ----
    int mi = (int)maskAcc;
#pragma unroll
    for (int off = 32; off > 0; off >>= 1) {
        accs[0] += __shfl_down(accs[0], off);
        accs[1] += __shfl_down(accs[1], off);
        accs[2] += __shfl_down(accs[2], off);
        accs[3] += __shfl_down(accs[3], off);
        accB    += __shfl_down(accB, off);
        mi      &= __shfl_down(mi, off);
    }
    if (lane == 0) {
        rS[wid][0] = accs[0]; rS[wid][1] = accs[1];
        rS[wid][2] = accs[2]; rS[wid][3] = accs[3];
        rS[wid][4] = accB;
        rM[wid] = mi;
    }
    __syncthreads();
    if (t == 0) {
        float s0 = 0.f, s1 = 0.f, s2 = 0.f, s3 = 0.f, sB = 0.f;
        int m = 0x1F;
#pragma unroll
        for (int w = 0; w < 4; ++w) {
            s0 += rS[w][0]; s1 += rS[w][1]; s2 += rS[w][2]; s3 += rS[w][3];
            sB += rS[w][4];
            m  &= rM[w];
        }
        float cnt = (float)nsamp;
        out[0 * NEDGE + e] = s0 / cnt;
        out[1 * NEDGE + e] = s1 / cnt;
        out[2 * NEDGE + e] = s2 / cnt;
        out[3 * NEDGE + e] = s3 / cnt;
        bool vm1 = m & 1;
#pragma unroll
        for (int s = 0; s < NSRC; ++s)
            out[NSRC * NEDGE + s * NEDGE + e] =
                (vm1 && ((m >> (s + 1)) & 1)) ? 1.f : 0.f;
        out[2 * NSRC * NEDGE + e] = ((sB / cnt) > 0.5f) ? 1.f : 0.f;
    }
}

extern "C" void kernel_launch(void* const* d_in, const int* in_sizes, int n_in,
                              void* d_out, int out_size, void* d_ws, size_t ws_size,
                              hipStream_t stream) {
    const float* start = (const float*)d_in[0];
    const float* endp  = (const float*)d_in[1];
    const float* imgs  = (const float*)d_in[2];
    const float* trans = (const float*)d_in[3];
    const float* K     = (const float*)d_in[4];
    const int*   npe   = (const int*)d_in[8];
    int P = in_sizes[5];

    int* bg = (int*)d_ws;              // 24000 B

    float* out = (float*)d_out;
    scan_kernel<<<1, 256, 0, stream>>>(npe, bg);
    points_kernel<<<NEDGE, 256, 0, stream>>>(start, endp, K, trans, npe, bg,
                                             imgs, out, P);
}